// Round 1
// baseline (40.381 us; speedup 1.0000x reference)
//
#include <hip/hip_runtime.h>
#include <math.h>

#define NB 64
#define NK 40
#define TDIM 16
#define IMH 96
#define IMW 96
#define HW (IMH*IMW)
#define PLANES (NK+1)

__global__ __launch_bounds__(256) void TemplateImageDecoder_kernel(
    const float* __restrict__ poses,
    const float* __restrict__ presences,
    const float* __restrict__ templates,
    const float* __restrict__ bg_value,
    const float* __restrict__ temperature_logit,
    float* __restrict__ out)
{
    const int tid = threadIdx.x;
    const int bid = blockIdx.x;
    const int b = bid / PLANES;
    const int k = bid - b * PLANES;

    // temperature = softplus(temperature_logit + 0.5) + 1e-4   (uniform scalar)
    const float tl = temperature_logit[0] + 0.5f;
    const float sp = (tl > 0.0f) ? (tl + log1pf(expf(-tl))) : log1pf(expf(tl));
    const float temperature = sp + 1e-4f;
    const float invT = 1.0f / temperature;

    const size_t plane = ((size_t)b * PLANES + k) * (size_t)HW;
    float* __restrict__ outL = out + plane;                                  // s=0: mixture_logits
    float* __restrict__ outM = out + (size_t)NB * PLANES * HW + plane;       // s=1: mixture_means

    if (k == NK) {
        // background plane: constant fill
        const float bg  = 1.0f / (1.0f + expf(-bg_value[0]));
        const float bgl = bg / temperature;
        const float4 vl = {bgl, bgl, bgl, bgl};
        const float4 vm = {bg,  bg,  bg,  bg};
        float4* __restrict__ oL = reinterpret_cast<float4*>(outL);
        float4* __restrict__ oM = reinterpret_cast<float4*>(outM);
        for (int g = tid; g < HW/4; g += 256) { oL[g] = vl; oM[g] = vm; }
        return;
    }

    // stage sigmoid(template_k) into LDS: 256 elements, one per thread
    __shared__ float tpl[TDIM*TDIM];
    {
        const float tv = templates[k*TDIM*TDIM + tid];
        tpl[tid] = 1.0f / (1.0f + __expf(-tv));
    }

    // uniform per-plane parameters
    const float* __restrict__ th = poses + ((size_t)b * NK + k) * 6;
    // ix = 8*grid_x + 7.5  where grid_x = t00*gx + t01*gy + t02  -> fold the *8+7.5
    const float ax = 8.0f*th[0], bx = 8.0f*th[1], cx = fmaf(8.0f, th[2], 7.5f);
    const float ay = 8.0f*th[3], by = 8.0f*th[4], cy = fmaf(8.0f, th[5], 7.5f);
    const float p  = presences[b*NK + k];
    const float lp = logf(fmaxf(p, 1e-16f));
    __syncthreads();

    // 4 pixels per thread per iteration; 96 % 4 == 0 so a group never crosses a row
    for (int g = tid; g < HW/4; g += 256) {
        const int h  = g / (IMW/4);
        const int w0 = (g - h*(IMW/4)) * 4;
        const float gy = (2.0f*h + 1.0f) * (1.0f/IMH) - 1.0f;
        float resM[4], resL[4];
        #pragma unroll
        for (int j = 0; j < 4; ++j) {
            const float gx = (2.0f*(w0 + j) + 1.0f) * (1.0f/IMW) - 1.0f;
            const float ix = fmaf(ax, gx, fmaf(bx, gy, cx));
            const float iy = fmaf(ay, gx, fmaf(by, gy, cy));
            const float x0f = floorf(ix), y0f = floorf(iy);
            const float fx = ix - x0f,   fy = iy - y0f;
            const int   x0 = (int)x0f,   y0 = (int)y0f;
            const float wx0 = 1.0f - fx, wy0 = 1.0f - fy;
            float acc = 0.0f;
            #pragma unroll
            for (int dy = 0; dy < 2; ++dy) {
                const int   y  = y0 + dy;
                const float wy = dy ? fy : wy0;
                const int   yc = min(max(y, 0), TDIM-1);
                #pragma unroll
                for (int dx = 0; dx < 2; ++dx) {
                    const int   x  = x0 + dx;
                    const float wx = dx ? fx : wx0;
                    const int   xc = min(max(x, 0), TDIM-1);
                    float v = tpl[yc*TDIM + xc];
                    v = ((unsigned)y < (unsigned)TDIM && (unsigned)x < (unsigned)TDIM) ? v : 0.0f;
                    acc = fmaf(v, wy*wx, acc);
                }
            }
            resM[j] = acc;
            resL[j] = fmaf(acc, invT, lp);
        }
        reinterpret_cast<float4*>(outM)[g] = make_float4(resM[0], resM[1], resM[2], resM[3]);
        reinterpret_cast<float4*>(outL)[g] = make_float4(resL[0], resL[1], resL[2], resL[3]);
    }
}

extern "C" void kernel_launch(void* const* d_in, const int* in_sizes, int n_in,
                              void* d_out, int out_size, void* d_ws, size_t ws_size,
                              hipStream_t stream) {
    const float* poses             = (const float*)d_in[0];
    const float* presences         = (const float*)d_in[1];
    const float* templates         = (const float*)d_in[2];
    const float* bg_value          = (const float*)d_in[3];
    const float* temperature_logit = (const float*)d_in[4];
    float* out = (float*)d_out;

    TemplateImageDecoder_kernel<<<dim3(NB*PLANES), dim3(256), 0, stream>>>(
        poses, presences, templates, bg_value, temperature_logit, out);
}

// Round 2
// 36.682 us; speedup vs baseline: 1.1008x; 1.1008x over previous
//
#include <hip/hip_runtime.h>
#include <math.h>

#define NB 64
#define NK 40
#define TDIM 16
#define IMH 96
#define IMW 96
#define HW (IMH*IMW)
#define PLANES (NK+1)
#define PSTR 20            // padded LDS row stride (19 rows used)
#define PROWS 19

__global__ __launch_bounds__(256) void TemplateImageDecoder_kernel(
    const float* __restrict__ poses,
    const float* __restrict__ presences,
    const float* __restrict__ templates,
    const float* __restrict__ bg_value,
    const float* __restrict__ temperature_logit,
    float* __restrict__ out)
{
    const int tid = threadIdx.x;
    const int bid = blockIdx.x;
    const int b = bid / PLANES;
    const int k = bid - b * PLANES;

    // temperature = softplus(temperature_logit + 0.5) + 1e-4 (uniform scalar)
    const float tl = temperature_logit[0] + 0.5f;
    const float sp = (tl > 0.0f) ? (tl + log1pf(expf(-tl))) : log1pf(expf(tl));
    const float invT = 1.0f / (sp + 1e-4f);

    const size_t plane = ((size_t)b * PLANES + k) * (size_t)HW;
    float4* __restrict__ outL4 = reinterpret_cast<float4*>(out + plane);
    float4* __restrict__ outM4 = reinterpret_cast<float4*>(out + (size_t)NB * PLANES * HW + plane);

    if (k == NK) {
        // background plane: constant fill
        const float bg  = 1.0f / (1.0f + expf(-bg_value[0]));
        const float bgl = bg * invT;
        const float4 vl = {bgl, bgl, bgl, bgl};
        const float4 vm = {bg,  bg,  bg,  bg};
        #pragma unroll 3
        for (int it = 0; it < 9; ++it) {
            const int g = tid + it * 256;
            outL4[g] = vl;
            outM4[g] = vm;
        }
        return;
    }

    // zero-padded sigmoid(template) in LDS: border rows/cols are 0 so
    // clamped-coordinate lookups reproduce the reference's OOB masking.
    __shared__ float P[PROWS * PSTR];
    for (int i = tid; i < PROWS * PSTR; i += 256) P[i] = 0.0f;
    __syncthreads();
    {
        const float tv = templates[k * TDIM * TDIM + tid];
        const int y = tid >> 4, x = tid & 15;
        P[(y + 1) * PSTR + (x + 1)] = 1.0f / (1.0f + __expf(-tv));
    }

    // uniform per-plane parameters
    const float* __restrict__ th = poses + ((size_t)b * NK + k) * 6;
    // ix = 8*(t00*gx + t01*gy + t02) + 7.5 ; fold the *8 and +7.5
    const float ax = 8.0f * th[0], bx_ = 8.0f * th[1], cx = fmaf(8.0f, th[2], 7.5f);
    const float ay = 8.0f * th[3], by_ = 8.0f * th[4], cy = fmaf(8.0f, th[5], 7.5f);
    const float sx = ax * (2.0f / IMW);   // ix step per pixel along w
    const float sy = ay * (2.0f / IMW);   // iy step per pixel along w
    const float p  = presences[b * NK + k];
    const float lp = logf(fmaxf(p, 1e-16f));
    __syncthreads();

    // 2304 float4-groups = 9 * 256: static trip count, no bounds check.
    #pragma unroll 3
    for (int it = 0; it < 9; ++it) {
        const int g  = tid + it * 256;
        const int h  = g / (IMW / 4);
        const int w0 = (g - h * (IMW / 4)) * 4;
        const float gy  = (2.0f * h + 1.0f) * (1.0f / IMH) - 1.0f;
        const float gx0 = (2.0f * w0 + 1.0f) * (1.0f / IMW) - 1.0f;
        const float ix0 = fmaf(ax, gx0, fmaf(bx_, gy, cx));
        const float iy0 = fmaf(ay, gx0, fmaf(by_, gy, cy));
        float rM[4], rL[4];
        #pragma unroll
        for (int j = 0; j < 4; ++j) {
            float ix = fmaf((float)j, sx, ix0);
            float iy = fmaf((float)j, sy, iy0);
            ix = fminf(fmaxf(ix, -1.0f), 16.0f);
            iy = fminf(fmaxf(iy, -1.0f), 16.0f);
            const float x0f = floorf(ix), y0f = floorf(iy);
            const float fx = ix - x0f,   fy = iy - y0f;
            const int   x0 = (int)x0f,   y0 = (int)y0f;
            const int base = (y0 + 1) * PSTR + (x0 + 1);
            const float v00 = P[base],        v01 = P[base + 1];
            const float v10 = P[base + PSTR], v11 = P[base + PSTR + 1];
            const float wx0 = 1.0f - fx, wy0 = 1.0f - fy;
            const float top = fmaf(fx, v01, wx0 * v00);
            const float bot = fmaf(fx, v11, wx0 * v10);
            const float acc = fmaf(fy, bot, wy0 * top);
            rM[j] = acc;
            rL[j] = fmaf(acc, invT, lp);
        }
        outM4[g] = make_float4(rM[0], rM[1], rM[2], rM[3]);
        outL4[g] = make_float4(rL[0], rL[1], rL[2], rL[3]);
    }
}

extern "C" void kernel_launch(void* const* d_in, const int* in_sizes, int n_in,
                              void* d_out, int out_size, void* d_ws, size_t ws_size,
                              hipStream_t stream) {
    const float* poses             = (const float*)d_in[0];
    const float* presences         = (const float*)d_in[1];
    const float* templates         = (const float*)d_in[2];
    const float* bg_value          = (const float*)d_in[3];
    const float* temperature_logit = (const float*)d_in[4];
    float* out = (float*)d_out;

    TemplateImageDecoder_kernel<<<dim3(NB * PLANES), dim3(256), 0, stream>>>(
        poses, presences, templates, bg_value, temperature_logit, out);
}